// Round 1
// baseline (187.858 us; speedup 1.0000x reference)
//
#include <hip/hip_runtime.h>

#define NBINS 10
#define NCLS  128
#define LBINS 384   // 3 * NCLS
// ws layout (floats): [0] = loss_sum, [1..10] = GD hist, [11..394] = label hist

__global__ __launch_bounds__(256) void ghm_main(
    const float* __restrict__ xg, const float* __restrict__ tg,
    const float* __restrict__ mask,
    const float* __restrict__ gd_ema, const float* __restrict__ lab_ema,
    float* __restrict__ ws, int n4)
{
    __shared__ float s_gd[NBINS];     // GD ema (weights table)
    __shared__ float s_lab[LBINS];    // label ema (weights table)
    __shared__ float s_hlab[LBINS];   // block label histogram
    __shared__ float s_hgd[NBINS];    // block GD histogram
    __shared__ float s_red[4];        // per-wave loss partials

    const int tid = threadIdx.x;
    if (tid < NBINS) { s_gd[tid] = gd_ema[tid]; s_hgd[tid] = 0.f; }
    for (int i = tid; i < LBINS; i += 256) { s_lab[i] = lab_ema[i]; s_hlab[i] = 0.f; }
    __syncthreads();

    float gdl[NBINS];
#pragma unroll
    for (int b = 0; b < NBINS; ++b) gdl[b] = 0.f;
    float loss_acc = 0.f;

    const float4* x4 = (const float4*)xg;
    const float4* t4 = (const float4*)tg;

    for (int i = blockIdx.x * 256 + tid; i < n4; i += gridDim.x * 256) {
        float4 xv = x4[i];
        float4 tv = t4[i];
        const int e0 = i << 2;           // first element index of this float4
        const float m = mask[e0 >> 7];   // mask index = element / 128 (C=128, 4 | 128)
        const int c0 = e0 & 127;         // class of first element
        float xs[4] = {xv.x, xv.y, xv.z, xv.w};
        float ts[4] = {tv.x, tv.y, tv.z, tv.w};
#pragma unroll
        for (int j = 0; j < 4; ++j) {
            float x  = xs[j];
            float tp = fminf(fmaxf(ts[j], 0.f), 1.f);       // LABEL_SMOOTHING = 0
            float E  = expf(-fabsf(x));                     // e^{-|x|}
            float raw = fmaxf(x, 0.f) - x * tp + log1pf(E); // stable BCE
            float inv = 1.f / (1.f + E);
            float p  = (x >= 0.f) ? inv : E * inv;          // sigmoid(x)
            float g  = fabsf(p - tp);                       // grad magnitude in [0,1]
            int bin = (int)(g * 10.f);                      // trunc == floor (g >= 0)
            bin = bin > 9 ? 9 : bin;
            int t3 = (int)(tp * 3.f);
            t3 = t3 > 2 ? 2 : t3;
            int li = (c0 + j) * 3 + t3;
            float w = rsqrtf(s_gd[bin] * s_lab[li]);        // sqrt(1/ge * 1/le)
            loss_acc += raw * w * m;
            atomicAdd(&s_hlab[li], m);                      // lanes hit distinct classes
#pragma unroll
            for (int b = 0; b < NBINS; ++b)                 // register GD histogram
                gdl[b] += (bin == b) ? m : 0.f;
        }
    }

    // ---- block reduction ----
    const int lane = tid & 63, wv = tid >> 6;
#pragma unroll
    for (int off = 32; off > 0; off >>= 1) loss_acc += __shfl_down(loss_acc, off);
    if (lane == 0) s_red[wv] = loss_acc;

#pragma unroll
    for (int b = 0; b < NBINS; ++b) {
        float v = gdl[b];
#pragma unroll
        for (int off = 32; off > 0; off >>= 1) v += __shfl_down(v, off);
        if (lane == 0) atomicAdd(&s_hgd[b], v);
    }
    __syncthreads();

    if (tid == 0) {
        float L = s_red[0] + s_red[1] + s_red[2] + s_red[3];
        atomicAdd(&ws[0], L);
    }
    if (tid < NBINS) atomicAdd(&ws[1 + tid], s_hgd[tid]);
    for (int i = tid; i < LBINS; i += 256) atomicAdd(&ws[1 + NBINS + i], s_hlab[i]);
}

__global__ __launch_bounds__(512) void ghm_fin(
    const float* __restrict__ ws,
    const float* __restrict__ gd_ema, const float* __restrict__ lab_ema,
    float* __restrict__ out)
{
    __shared__ float red[512];
    __shared__ float s_ge[NBINS];
    __shared__ float s_gsum;
    __shared__ float s_gesum;

    const int tid = threadIdx.x;

    // label histogram value + sum
    float h = (tid < LBINS) ? ws[1 + NBINS + tid] : 0.f;
    red[tid] = h;
    __syncthreads();
    for (int off = 256; off > 0; off >>= 1) {
        if (tid < off) red[tid] += red[tid + off];
        __syncthreads();
    }
    const float lab_sum = red[0];
    __syncthreads();

    // GD histogram value + sum (10 bins, serial in thread 0 via LDS)
    float gh = (tid < NBINS) ? ws[1 + tid] : 0.f;
    red[tid] = gh;
    __syncthreads();
    if (tid == 0) {
        float s = 0.f;
        for (int b = 0; b < NBINS; ++b) s += red[b];
        s_gsum = s;
    }
    __syncthreads();
    const float gd_sum = s_gsum;   // == m.sum()

    // GD EMA update
    if (tid < NBINS) {
        float hn = gh / fmaxf(gd_sum, 1e-10f) * (float)NBINS;
        s_ge[tid] = gd_ema[tid] * 0.999f + 0.001f * hn;
    }
    __syncthreads();
    if (tid == 0) {
        float s = 0.f;
        for (int b = 0; b < NBINS; ++b) s += s_ge[b];
        s_gesum = s;
        out[0] = ws[0] / fmaxf(gd_sum, 1e-10f);   // loss
    }
    __syncthreads();
    if (tid < NBINS)
        out[1 + tid] = s_ge[tid] / fmaxf(s_gesum, 1e-10f) * (float)NBINS;

    // label EMA update
    float e_lab = 0.f;
    if (tid < LBINS) {
        float hn = h / fmaxf(lab_sum, 1e-10f) * (float)LBINS;
        e_lab = lab_ema[tid] * 0.999f + 0.001f * hn;
    }
    __syncthreads();
    red[tid] = e_lab;
    __syncthreads();
    for (int off = 256; off > 0; off >>= 1) {
        if (tid < off) red[tid] += red[tid + off];
        __syncthreads();
    }
    const float e_sum = red[0];
    if (tid < LBINS)
        out[1 + NBINS + tid] = e_lab / fmaxf(e_sum, 1e-10f) * (float)LBINS;
}

extern "C" void kernel_launch(void* const* d_in, const int* in_sizes, int n_in,
                              void* d_out, int out_size, void* d_ws, size_t ws_size,
                              hipStream_t stream)
{
    const float* logits  = (const float*)d_in[0];
    const float* tprob   = (const float*)d_in[1];
    const float* mask    = (const float*)d_in[2];
    const float* gd_ema  = (const float*)d_in[3];
    const float* lab_ema = (const float*)d_in[4];
    float* out = (float*)d_out;
    float* ws  = (float*)d_ws;

    const int n  = in_sizes[0];      // 16*4096*128
    const int n4 = n >> 2;

    hipMemsetAsync(ws, 0, (1 + NBINS + LBINS) * sizeof(float), stream);
    ghm_main<<<1024, 256, 0, stream>>>(logits, tprob, mask, gd_ema, lab_ema, ws, n4);
    ghm_fin<<<1, 512, 0, stream>>>(ws, gd_ema, lab_ema, out);
}

// Round 2
// 149.479 us; speedup vs baseline: 1.2568x; 1.2568x over previous
//
#include <hip/hip_runtime.h>

#define NBINS 10
#define NCLS  128
#define LBINS 384          // 3 * NCLS
#define NSLICE 8           // ws slices to spread global atomic traffic
#define SLICE_STRIDE 512   // floats per slice: [0]=loss, [1..10]=gd, [11..394]=lab
#define GRID 2048
#define BLOCK 256

__global__ __launch_bounds__(256) void ghm_main(
    const float* __restrict__ xg, const float* __restrict__ tg,
    const float* __restrict__ mask,
    const float* __restrict__ gd_ema, const float* __restrict__ lab_ema,
    float* __restrict__ ws, int n4)
{
    __shared__ float s_gd[NBINS];     // GD ema weight table
    __shared__ float s_lab[LBINS];    // label ema weight table (staging only)
    __shared__ float s_hlab[LBINS];   // block label histogram (flush only)
    __shared__ float s_hgd[NBINS];    // block GD histogram (flush only)
    __shared__ float s_red[4];

    const int tid = threadIdx.x;
    if (tid < NBINS) { s_gd[tid] = gd_ema[tid]; s_hgd[tid] = 0.f; }
    for (int i = tid; i < LBINS; i += BLOCK) { s_lab[i] = lab_ema[i]; s_hlab[i] = 0.f; }
    __syncthreads();

    // Each thread's 4 consecutive classes are FIXED across grid-stride iters:
    // e0 = 4*i, i = b*256 + tid + k*GRID*256; 4*256 = 1024 == 0 mod 128.
    const int c0 = (4 * tid) & 127;
    float wl[4][3];
#pragma unroll
    for (int j = 0; j < 4; ++j)
#pragma unroll
        for (int t = 0; t < 3; ++t) wl[j][t] = s_lab[(c0 + j) * 3 + t];

    float lab[4][3] = {{0.f}};        // register label histogram
    float gdl[NBINS] = {0.f};         // register GD histogram
    float loss_acc = 0.f;

    const float4* x4 = (const float4*)xg;
    const float4* t4 = (const float4*)tg;
    const int i0 = blockIdx.x * BLOCK + tid;

    // Load all 4 iterations up front (8 float4s in flight -> MLP)
    float4 xv[4], tv[4]; float mv[4];
#pragma unroll
    for (int k = 0; k < 4; ++k) {
        int i = i0 + k * (GRID * BLOCK);
        bool ok = i < n4;
        int is = ok ? i : 0;
        xv[k] = x4[is];
        tv[k] = t4[is];
        mv[k] = ok ? mask[is >> 5] : 0.f;   // mask idx = (4i)/128 = i/32
    }

#pragma unroll
    for (int k = 0; k < 4; ++k) {
        const float m = mv[k];
        float xs[4] = {xv[k].x, xv[k].y, xv[k].z, xv[k].w};
        float ts[4] = {tv[k].x, tv[k].y, tv[k].z, tv[k].w};
#pragma unroll
        for (int j = 0; j < 4; ++j) {
            float x  = xs[j];
            float tp = fminf(fmaxf(ts[j], 0.f), 1.f);
            float ax = fabsf(x);
            float E  = __expf(-ax);                         // e^{-|x|}
            float raw = fmaxf(x, 0.f) - x * tp + __logf(1.f + E);
            float inv = __builtin_amdgcn_rcpf(1.f + E);
            float p  = (x >= 0.f) ? inv : E * inv;          // sigmoid(x)
            float g  = fabsf(p - tp);
            int bin = (int)(g * 10.f); bin = bin > 9 ? 9 : bin;
            int t3  = (int)(tp * 3.f); t3 = t3 > 2 ? 2 : t3;
            float wlj = (t3 == 0) ? wl[j][0] : ((t3 == 1) ? wl[j][1] : wl[j][2]);
            float w = __builtin_amdgcn_rsqf(s_gd[bin] * wlj);
            loss_acc += raw * w * m;
#pragma unroll
            for (int t = 0; t < 3; ++t) lab[j][t] += (t3 == t) ? m : 0.f;
#pragma unroll
            for (int b = 0; b < NBINS; ++b) gdl[b] += (bin == b) ? m : 0.f;
        }
    }

    // ---- block reduction ----
    const int lane = tid & 63, wv = tid >> 6;
    float v = loss_acc;
#pragma unroll
    for (int off = 32; off > 0; off >>= 1) v += __shfl_down(v, off);
    if (lane == 0) s_red[wv] = v;

#pragma unroll
    for (int b = 0; b < NBINS; ++b) {
        float g = gdl[b];
#pragma unroll
        for (int off = 32; off > 0; off >>= 1) g += __shfl_down(g, off);
        if (lane == 0) atomicAdd(&s_hgd[b], g);
    }

    // label: 12 LDS atomics per thread, once per block (8 threads share a class set)
#pragma unroll
    for (int j = 0; j < 4; ++j)
#pragma unroll
        for (int t = 0; t < 3; ++t)
            atomicAdd(&s_hlab[(c0 + j) * 3 + t], lab[j][t]);
    __syncthreads();

    float* wss = ws + (blockIdx.x & (NSLICE - 1)) * SLICE_STRIDE;
    if (tid == 0) atomicAdd(&wss[0], s_red[0] + s_red[1] + s_red[2] + s_red[3]);
    if (tid < NBINS) atomicAdd(&wss[1 + tid], s_hgd[tid]);
    for (int i = tid; i < LBINS; i += BLOCK) atomicAdd(&wss[1 + NBINS + i], s_hlab[i]);
}

__global__ __launch_bounds__(512) void ghm_fin(
    const float* __restrict__ ws,
    const float* __restrict__ gd_ema, const float* __restrict__ lab_ema,
    float* __restrict__ out)
{
    __shared__ float red[512];
    __shared__ float s_gde[NBINS];
    __shared__ float s_gesum;

    const int tid = threadIdx.x;

    // merge slices
    float v = 0.f;
    if (tid < 1 + NBINS + LBINS) {
#pragma unroll
        for (int s = 0; s < NSLICE; ++s) v += ws[s * SLICE_STRIDE + tid];
    }

    // msum = sum of GD hist (== m.sum() == label hist sum)
    red[tid] = (tid >= 1 && tid < 1 + NBINS) ? v : 0.f;
    __syncthreads();
    for (int off = 256; off > 0; off >>= 1) {
        if (tid < off) red[tid] += red[tid + off];
        __syncthreads();
    }
    const float msum = red[0];
    __syncthreads();
    const float inv_m = 1.f / fmaxf(msum, 1e-10f);

    if (tid == 0) out[0] = v * inv_m;   // loss (v at tid 0 is loss_sum)

    // GD EMA
    if (tid >= 1 && tid < 1 + NBINS) {
        float hn = v * inv_m * (float)NBINS;
        s_gde[tid - 1] = gd_ema[tid - 1] * 0.999f + 0.001f * hn;
    }
    __syncthreads();
    if (tid == 0) {
        float s = 0.f;
        for (int b = 0; b < NBINS; ++b) s += s_gde[b];
        s_gesum = s;
    }
    __syncthreads();
    if (tid >= 1 && tid < 1 + NBINS)
        out[tid] = s_gde[tid - 1] / fmaxf(s_gesum, 1e-10f) * (float)NBINS;

    // label EMA
    float e = 0.f;
    if (tid >= 1 + NBINS && tid < 1 + NBINS + LBINS) {
        float hn = v * inv_m * (float)LBINS;   // lab_sum == msum
        e = lab_ema[tid - 1 - NBINS] * 0.999f + 0.001f * hn;
    }
    red[tid] = e;
    __syncthreads();
    for (int off = 256; off > 0; off >>= 1) {
        if (tid < off) red[tid] += red[tid + off];
        __syncthreads();
    }
    const float esum = red[0];
    if (tid >= 1 + NBINS && tid < 1 + NBINS + LBINS)
        out[tid] = e / fmaxf(esum, 1e-10f) * (float)LBINS;
}

extern "C" void kernel_launch(void* const* d_in, const int* in_sizes, int n_in,
                              void* d_out, int out_size, void* d_ws, size_t ws_size,
                              hipStream_t stream)
{
    const float* logits  = (const float*)d_in[0];
    const float* tprob   = (const float*)d_in[1];
    const float* mask    = (const float*)d_in[2];
    const float* gd_ema  = (const float*)d_in[3];
    const float* lab_ema = (const float*)d_in[4];
    float* out = (float*)d_out;
    float* ws  = (float*)d_ws;

    const int n  = in_sizes[0];
    const int n4 = n >> 2;

    hipMemsetAsync(ws, 0, NSLICE * SLICE_STRIDE * sizeof(float), stream);
    ghm_main<<<GRID, BLOCK, 0, stream>>>(logits, tprob, mask, gd_ema, lab_ema, ws, n4);
    ghm_fin<<<1, 512, 0, stream>>>(ws, gd_ema, lab_ema, out);
}